// Round 1
// baseline (117.106 us; speedup 1.0000x reference)
//
#include <hip/hip_runtime.h>

// Trilinear 3D-LUT interpolation (image-adaptive-3DLUT forward).
// lut: [3, 33, 33, 33] fp32, x: [4, 3, 1024, 1024] fp32 in [0,1], out same as x.
//
// R4: single-kernel version. R3's profile showed both our kernels below the
// 42 us harness fills (256 MiB ws poison) while dur_us=117 -> the timed graph
// contains harness resets. Changes:
//  - NO workspace, NO pack kernel: stage the raw fp32 LUT channel directly
//    into LDS via global_load_lds dwordx4 (fp16-pair array was the SAME size
//    as fp32 because it duplicated values). Misaligned channel bases handled
//    with an aligned 16B base + uniform 'off' added to every gather index.
//  - gathers read r-adjacent pairs L[i],L[i+1] -> compiler fuses to
//    ds_read2_b32: same 16 LDS instructions/iter as R3, zero pack/unpack VALU,
//    exact fp32 (absmax should drop from 2e-3 to ~1e-6).
//  - keeps R3's wins: hoisted global loads, batched gathers, XCD swizzle
//    (3 channel-blocks of a chunk share x in one XCD's L2), nontemporal stores.

#define LUT_D      33
#define LUT_DD     (LUT_D * LUT_D)            // 1089
#define LUT_N      (LUT_D * LUT_D * LUT_D)    // 35937
#define HW4        (1024 * 1024 / 4)          // 262144 float4 groups per plane
#define NGROUPS    (4 * HW4)                  // 1048576 groups per channel-pass
#define NCHUNKS    256
#define THREADS    1024
#define ITERS      (NGROUPS / NCHUNKS / THREADS)  // 4
#define STAGE_FULL 8984                       // full 16B groups = 35936 floats
#define LDS_FLOATS 35940                      // 143,760 B (1 block/CU)

typedef float vfloat4 __attribute__((ext_vector_type(4)));

__global__ __launch_bounds__(THREADS)
void lut3d_trilerp_kernel(const float* __restrict__ lut,
                          const float* __restrict__ x,
                          float* __restrict__ out) {
    extern __shared__ __align__(16) float P[];  // LDS_FLOATS floats

    const int bx   = blockIdx.x;
    // XCD-swizzle: blocks {g*24 + 8c + xcd} for c=0..2 share chunk g*8+xcd and
    // land on the same XCD (bx % 8 equal) -> x chunk shared in that L2.
    const int xcd   = bx & 7;
    const int c     = (bx >> 3) % 3;
    const int chunk = (bx / 24) * 8 + xcd;   // [0, 256)

    // ---- Stage fp32 LUT channel c into LDS.
    // Channel byte base c*143748 is only 4B-aligned; use aligned base and a
    // uniform element offset off = (c*LUT_N) & 3 in {0,1,2}.
    const int f0  = c * LUT_N;
    const int off = f0 & 3;
    const float* ga = lut + (f0 - off);      // 16B-aligned source

    for (int s = 0; s < 9; ++s) {
        const int gid = s * THREADS + (int)threadIdx.x;
        if (gid < STAGE_FULL) {
            __builtin_amdgcn_global_load_lds(
                (const __attribute__((address_space(1))) void*)(ga + gid * 4),
                (__attribute__((address_space(3))) void*)(P + gid * 4),
                16, 0, 0);
        }
    }
    // Tail: relative floats 35936..35938 (idx 35939 never read; max used index
    // is off+35936 <= 35938). ga[35936+2] for c=2 is exactly the last element
    // of lut -> no OOB.
    if (threadIdx.x < 3) {
        P[STAGE_FULL * 4 + threadIdx.x] = ga[STAGE_FULL * 4 + threadIdx.x];
    }
    __syncthreads();  // drains vmcnt (global_load_lds) + lgkmcnt (tail write)

    const float* L = P + off;   // L[i] == lut[c*LUT_N + i]

    const float4* x4 = (const float4*)x;
    float4*       o4 = (float4*)out;

    const int g0 = chunk * (NGROUPS / NCHUNKS) + (int)threadIdx.x;

    // Phase A: hoist ALL global loads (12 float4 in flight).
    float4 R[ITERS], G[ITERS], B[ITERS];
    int obase[ITERS];
#pragma unroll
    for (int it = 0; it < ITERS; ++it) {
        const int g     = g0 + it * THREADS;
        const int b_img = g >> 18;            // g / HW4  (HW4 = 2^18)
        const int hw4   = g & (HW4 - 1);
        const int ibase = b_img * 3 * HW4 + hw4;
        R[it] = x4[ibase];
        G[it] = x4[ibase + HW4];
        B[it] = x4[ibase + 2 * HW4];
        obase[it] = ibase + c * HW4;          // (b_img*3 + c)*HW4 + hw4
    }

    // Phase B: per iteration, compute indices, batch-issue gathers, then math.
#pragma unroll
    for (int it = 0; it < ITERS; ++it) {
        const float rr[4] = {R[it].x, R[it].y, R[it].z, R[it].w};
        const float gg[4] = {G[it].x, G[it].y, G[it].z, G[it].w};
        const float bb[4] = {B[it].x, B[it].y, B[it].z, B[it].w};

        int   idx[4];
        float dr[4], dg[4], db[4];
#pragma unroll
        for (int k = 0; k < 4; ++k) {
            const float sr = rr[k] * 32.0f;
            const float sg = gg[k] * 32.0f;
            const float sb = bb[k] * 32.0f;
            const float fr = fminf(fmaxf(floorf(sr), 0.0f), 31.0f);
            const float fg = fminf(fmaxf(floorf(sg), 0.0f), 31.0f);
            const float fb = fminf(fmaxf(floorf(sb), 0.0f), 31.0f);
            dr[k] = sr - fr;
            dg[k] = sg - fg;
            db[k] = sb - fb;
            idx[k] = ((int)fb * LUT_D + (int)fg) * LUT_D + (int)fr;
        }

        // 8 corners per pixel as 4 adjacent fp32 pairs -> 4x ds_read2_b32.
        float c000[4], c001[4], c010[4], c011[4];
        float c100[4], c101[4], c110[4], c111[4];
#pragma unroll
        for (int k = 0; k < 4; ++k) {
            const float* p = L + idx[k];
            c000[k] = p[0];
            c001[k] = p[1];
            c010[k] = p[LUT_D];
            c011[k] = p[LUT_D + 1];
            c100[k] = p[LUT_DD];
            c101[k] = p[LUT_DD + 1];
            c110[k] = p[LUT_DD + LUT_D];
            c111[k] = p[LUT_DD + LUT_D + 1];
        }

        float oo[4];
#pragma unroll
        for (int k = 0; k < 4; ++k) {
            const float l00 = c000[k] + dr[k] * (c001[k] - c000[k]);
            const float l01 = c010[k] + dr[k] * (c011[k] - c010[k]);
            const float l10 = c100[k] + dr[k] * (c101[k] - c100[k]);
            const float l11 = c110[k] + dr[k] * (c111[k] - c110[k]);
            const float l0  = l00 + dg[k] * (l01 - l00);
            const float l1  = l10 + dg[k] * (l11 - l10);
            oo[k] = l0 + db[k] * (l1 - l0);
        }

        vfloat4 v = {oo[0], oo[1], oo[2], oo[3]};
        __builtin_nontemporal_store(v, (vfloat4*)&o4[obase[it]]);
    }
}

extern "C" void kernel_launch(void* const* d_in, const int* in_sizes, int n_in,
                              void* d_out, int out_size, void* d_ws, size_t ws_size,
                              hipStream_t stream) {
    const float* lut = (const float*)d_in[0];   // [3, 33, 33, 33]
    const float* x   = (const float*)d_in[1];   // [4, 3, 1024, 1024]
    float*       out = (float*)d_out;
    (void)d_ws; (void)ws_size;                  // workspace intentionally unused

    const int grid = 3 * NCHUNKS;                        // 768
    const size_t lds_bytes = LDS_FLOATS * sizeof(float); // 143,760 B
    lut3d_trilerp_kernel<<<grid, THREADS, lds_bytes, stream>>>(lut, x, out);
}